// Round 3
// baseline (247.559 us; speedup 1.0000x reference)
//
#include <hip/hip_runtime.h>
#include <math.h>

#define BATCH 8192
#define NU 512      // NUM_UNITS
#define NIN 256     // NUM_IN

__device__ __forceinline__ float2 cmul(float2 a, float2 b){
    return make_float2(a.x*b.x - a.y*b.y, a.x*b.y + a.y*b.x);
}

// ---------------- Kernel A: P = inputs @ w_ih^T  (8192x256 * 256x1024) ----
// f32 LDS-tiled GEMM, 64x64 tile, 256 threads, 4x4 per thread.
__global__ __launch_bounds__(256) void gemm_f32(const float* __restrict__ A,
                                                const float* __restrict__ W,
                                                float* __restrict__ P){
    __shared__ float As[16][65];
    __shared__ float Bs[16][65];
    const int tid = threadIdx.x;
    const int bx = blockIdx.x;   // 0..15  (cols of 1024, 64 each)
    const int by = blockIdx.y;   // 0..127 (rows of 8192, 64 each)
    const int tx = tid & 15, ty = tid >> 4;
    const int r  = tid >> 2, kq = (tid & 3) << 2;

    float acc[4][4] = {};
    const float* Aptr = A + (size_t)(by*64 + r)*NIN + kq;
    const float* Wptr = W + (size_t)(bx*64 + r)*NIN + kq;

    for (int kb = 0; kb < NIN; kb += 16){
        float4 av = *(const float4*)(Aptr + kb);
        float4 bv = *(const float4*)(Wptr + kb);
        As[kq+0][r] = av.x; As[kq+1][r] = av.y; As[kq+2][r] = av.z; As[kq+3][r] = av.w;
        Bs[kq+0][r] = bv.x; Bs[kq+1][r] = bv.y; Bs[kq+2][r] = bv.z; Bs[kq+3][r] = bv.w;
        __syncthreads();
        #pragma unroll
        for (int k = 0; k < 16; ++k){
            float a0 = As[k][ty*4+0], a1 = As[k][ty*4+1], a2 = As[k][ty*4+2], a3 = As[k][ty*4+3];
            float b0 = Bs[k][tx*4+0], b1 = Bs[k][tx*4+1], b2 = Bs[k][tx*4+2], b3 = Bs[k][tx*4+3];
            acc[0][0] += a0*b0; acc[0][1] += a0*b1; acc[0][2] += a0*b2; acc[0][3] += a0*b3;
            acc[1][0] += a1*b0; acc[1][1] += a1*b1; acc[1][2] += a1*b2; acc[1][3] += a1*b3;
            acc[2][0] += a2*b0; acc[2][1] += a2*b1; acc[2][2] += a2*b2; acc[2][3] += a2*b3;
            acc[3][0] += a3*b0; acc[3][1] += a3*b1; acc[3][2] += a3*b2; acc[3][3] += a3*b3;
        }
        __syncthreads();
    }
    #pragma unroll
    for (int i = 0; i < 4; ++i){
        float4 v = make_float4(acc[i][0], acc[i][1], acc[i][2], acc[i][3]);
        *(float4*)(P + (size_t)(by*64 + ty*4 + i)*1024 + bx*64 + tx*4) = v;
    }
}

// ---------------- Kernel B: per-row URNN pipeline -------------------------
// 1 block = 1 batch row, 256 threads. 512-pt radix-2 FFT in LDS.

template<int CONJ>
__device__ __forceinline__ void fft512(float2* buf, const float2* twid, int t){
    #pragma unroll
    for (int s = 1; s <= 9; ++s){
        int half = 1 << (s-1);
        int j  = t & (half-1);
        int i1 = ((t >> (s-1)) << s) + j;
        int i2 = i1 + half;
        float2 w = twid[j << (9-s)];
        if (CONJ) w.y = -w.y;
        float2 a  = buf[i1];
        float2 bb = cmul(w, buf[i2]);
        buf[i1] = make_float2(a.x+bb.x, a.y+bb.y);
        buf[i2] = make_float2(a.x-bb.x, a.y-bb.y);
        __syncthreads();
    }
}

__device__ __forceinline__ void reflect(float2* buf, const float* __restrict__ vre,
                                        const float* __restrict__ vim,
                                        float* red, int t){
    float2 z0 = buf[t], z1 = buf[t+256];
    float2 v0 = make_float2(vre[t],     vim[t]);
    float2 v1 = make_float2(vre[t+256], vim[t+256]);
    // conj(v)*z partials + |v|^2 partial
    float pr = v0.x*z0.x + v0.y*z0.y + v1.x*z1.x + v1.y*z1.y;
    float pi = v0.x*z0.y - v0.y*z0.x + v1.x*z1.y - v1.y*z1.x;
    float nn = v0.x*v0.x + v0.y*v0.y + v1.x*v1.x + v1.y*v1.y;
    #pragma unroll
    for (int off = 32; off > 0; off >>= 1){
        pr += __shfl_down(pr, off);
        pi += __shfl_down(pi, off);
        nn += __shfl_down(nn, off);
    }
    int wave = t >> 6;
    if ((t & 63) == 0){ red[wave*3+0] = pr; red[wave*3+1] = pi; red[wave*3+2] = nn; }
    __syncthreads();
    pr = red[0] + red[3] + red[6] + red[9];
    pi = red[1] + red[4] + red[7] + red[10];
    nn = red[2] + red[5] + red[8] + red[11];
    float coef = 2.0f / nn;
    float2 c = make_float2(coef*pr, coef*pi);
    float2 d0 = cmul(c, v0), d1v = cmul(c, v1);
    buf[t]     = make_float2(z0.x - d0.x,  z0.y - d0.y);
    buf[t+256] = make_float2(z1.x - d1v.x, z1.y - d1v.y);
    __syncthreads();
}

__global__ __launch_bounds__(256) void urnn_kernel(
        const float* __restrict__ states,
        const float* __restrict__ b_h,
        const float* __restrict__ d1_w,
        const float* __restrict__ r1_re, const float* __restrict__ r1_im,
        const int* __restrict__ perm,
        const float* __restrict__ d2_w,
        const float* __restrict__ r2_re, const float* __restrict__ r2_im,
        const float* __restrict__ d3_w,
        float* __restrict__ out /* in: inputs_mul, out: result */)
{
    __shared__ float2 bufA[512];
    __shared__ float2 bufB[512];
    __shared__ float2 twid[256];
    __shared__ float  red[12];
    const int t = threadIdx.x;
    const int b = blockIdx.x;

    // twiddle table exp(-2*pi*i*k/512), k=0..255
    {
        float ang = -6.283185307179586f * (float)t / 512.0f;
        float sn, cs; __sincosf(ang, &sn, &cs);
        twid[t] = make_float2(cs, sn);
    }

    // load state row, diag1, bit-reversed store
    {
        float4 s4 = ((const float4*)(states + (size_t)b*1024))[t];
        float2 dw = ((const float2*)d1_w)[t];   // d1_w[2t], d1_w[2t+1]
        float sn, cs;
        __sincosf(dw.x, &sn, &cs);
        float2 z0 = cmul(make_float2(cs, sn), make_float2(s4.x, s4.y));
        __sincosf(dw.y, &sn, &cs);
        float2 z1 = cmul(make_float2(cs, sn), make_float2(s4.z, s4.w));
        bufA[__brev(2*t)   >> 23] = z0;
        bufA[__brev(2*t+1) >> 23] = z1;
    }
    __syncthreads();

    fft512<0>(bufA, twid, t);                 // forward FFT
    reflect(bufA, r1_re, r1_im, red, t);      // reflection 1

    // permutation + diag2, bit-reversed store into bufB
    #pragma unroll
    for (int q = 0; q < 2; ++q){
        int i = t + q*256;
        int src = perm[i];
        float2 zv = bufA[src];
        float sn, cs; __sincosf(d2_w[i], &sn, &cs);
        zv = cmul(make_float2(cs, sn), zv);
        bufB[__brev(i) >> 23] = zv;
    }
    __syncthreads();

    fft512<1>(bufB, twid, t);                 // inverse FFT (unscaled)
    reflect(bufB, r2_re, r2_im, red, t);      // reflection 2

    // diag3 * (1/512) + inputs_mul + modReLU
    float* orow = out + (size_t)b*1024;
    const float inv = 1.0f/512.0f;
    float2 res0, res1;
    {
        float2 c0 = ((const float2*)orow)[t];        // complex u=t
        float2 z0 = bufB[t];
        float sn, cs; __sincosf(d3_w[t], &sn, &cs);
        float2 zz = cmul(make_float2(cs, sn), z0);
        float2 pre = make_float2(c0.x + zz.x*inv, c0.y + zz.y*inv);
        float norm = sqrtf(pre.x*pre.x + pre.y*pre.y);
        float sc = fmaxf(norm + b_h[t], 0.0f) / (norm + 1e-6f);
        res0 = make_float2(sc*pre.x, sc*pre.y);
    }
    {
        float2 c1 = ((const float2*)orow)[t+256];    // complex u=t+256
        float2 z1 = bufB[t+256];
        float sn, cs; __sincosf(d3_w[t+256], &sn, &cs);
        float2 zz = cmul(make_float2(cs, sn), z1);
        float2 pre = make_float2(c1.x + zz.x*inv, c1.y + zz.y*inv);
        float norm = sqrtf(pre.x*pre.x + pre.y*pre.y);
        float sc = fmaxf(norm + b_h[t+256], 0.0f) / (norm + 1e-6f);
        res1 = make_float2(sc*pre.x, sc*pre.y);
    }
    __syncthreads();   // all inputs_mul reads complete before overwrite
    orow[t]       = res0.x;
    orow[t+512]   = res0.y;
    orow[t+256]   = res1.x;
    orow[t+768]   = res1.y;
}

extern "C" void kernel_launch(void* const* d_in, const int* in_sizes, int n_in,
                              void* d_out, int out_size, void* d_ws, size_t ws_size,
                              hipStream_t stream) {
    const float* inputs = (const float*)d_in[0];
    const float* states = (const float*)d_in[1];
    const float* w_ih   = (const float*)d_in[2];
    const float* b_h    = (const float*)d_in[3];
    const float* d1_w   = (const float*)d_in[4];
    const float* r1_re  = (const float*)d_in[5];
    const float* r1_im  = (const float*)d_in[6];
    const int*   perm   = (const int*)d_in[7];
    const float* d2_w   = (const float*)d_in[8];
    const float* r2_re  = (const float*)d_in[9];
    const float* r2_im  = (const float*)d_in[10];
    const float* d3_w   = (const float*)d_in[11];
    float* out = (float*)d_out;

    dim3 gA(16, 128);
    gemm_f32<<<gA, 256, 0, stream>>>(inputs, w_ih, out);
    urnn_kernel<<<BATCH, 256, 0, stream>>>(states, b_h, d1_w, r1_re, r1_im,
                                           perm, d2_w, r2_re, r2_im, d3_w, out);
}

// Round 5
// 187.143 us; speedup vs baseline: 1.3228x; 1.3228x over previous
//
#include <hip/hip_runtime.h>
#include <math.h>

#define BATCH 8192
#define NU 512      // NUM_UNITS
#define NIN 256     // NUM_IN

typedef __attribute__((ext_vector_type(8))) __bf16 bf16x8;
typedef __attribute__((ext_vector_type(4))) float f32x4;

__device__ __forceinline__ float2 cmul(float2 a, float2 b){
    return make_float2(a.x*b.x - a.y*b.y, a.x*b.y + a.y*b.x);
}

// pack two f32 -> two bf16 (RNE) in one uint
__device__ __forceinline__ unsigned int pack2bf(float x, float y){
    unsigned int ux = __float_as_uint(x);
    ux = (ux + 0x7FFFu + ((ux >> 16) & 1u)) >> 16;
    unsigned int uy = __float_as_uint(y);
    uy = (uy + 0x7FFFu + ((uy >> 16) & 1u)) & 0xFFFF0000u;
    return ux | uy;
}

// ---------------- Kernel A: P = inputs @ w_ih^T via bf16 MFMA -------------
// 128x128 tile, BK=64, 256 threads (4 waves 2x2), XOR-swizzled LDS.
// Stages f32 global -> bf16 LDS with in-register RNE conversion.

// G: row-major [>=128 rows][NIN], stage rows 0..127, cols kb..kb+63 as bf16
__device__ __forceinline__ void stage_tile(const float* __restrict__ G,
                                           char* __restrict__ lds,
                                           int kb, int tid){
    const int r0 = tid >> 3;          // 0..31
    const int kc = (tid & 7) << 3;    // 0..56, 8 floats per thread
    #pragma unroll
    for (int it = 0; it < 4; ++it){
        const int row = r0 + (it << 5);
        const float* g = G + (size_t)row * NIN + kb + kc;
        float4 v0 = *(const float4*)g;
        float4 v1 = *(const float4*)(g + 4);
        int4 w;
        w.x = (int)pack2bf(v0.x, v0.y);
        w.y = (int)pack2bf(v0.z, v0.w);
        w.z = (int)pack2bf(v1.x, v1.y);
        w.w = (int)pack2bf(v1.z, v1.w);
        int off = (row << 7) + (kc << 1);   // row*128B + kc*2B
        off ^= (row & 7) << 4;              // st-style XOR swizzle
        *(int4*)(lds + off) = w;
    }
}

__global__ __launch_bounds__(256) void gemm_bf16(const float* __restrict__ A,
                                                 const float* __restrict__ W,
                                                 float* __restrict__ P){
    __shared__ __align__(16) char As[128*64*2];
    __shared__ __align__(16) char Bs[128*64*2];
    const int tid  = threadIdx.x;
    const int lane = tid & 63, wv = tid >> 6;
    const int wm = wv >> 1, wn = wv & 1;     // 2x2 wave grid, 64x64 each
    const int bm = blockIdx.y, bn = blockIdx.x;

    const float* Ag = A + (size_t)bm * 128 * NIN;
    const float* Wg = W + (size_t)bn * 128 * NIN;

    f32x4 acc[4][4] = {};
    const int frow = lane & 15;
    const int kq   = (lane >> 4) << 4;       // byte offset of 8-bf16 k-group

    for (int kb = 0; kb < NIN; kb += 64){
        if (kb) __syncthreads();
        stage_tile(Ag, As, kb, tid);
        stage_tile(Wg, Bs, kb, tid);
        __syncthreads();
        #pragma unroll
        for (int ks = 0; ks < 2; ++ks){
            const int koff = kq + (ks << 6);
            bf16x8 a[4], b[4];
            #pragma unroll
            for (int i = 0; i < 4; ++i){
                const int ar = wm*64 + i*16 + frow;
                a[i] = *(const bf16x8*)(As + (((ar << 7) + koff) ^ ((ar & 7) << 4)));
                const int br = wn*64 + i*16 + frow;
                b[i] = *(const bf16x8*)(Bs + (((br << 7) + koff) ^ ((br & 7) << 4)));
            }
            #pragma unroll
            for (int mi = 0; mi < 4; ++mi)
                #pragma unroll
                for (int ni = 0; ni < 4; ++ni)
                    acc[mi][ni] = __builtin_amdgcn_mfma_f32_16x16x32_bf16(
                        a[mi], b[ni], acc[mi][ni], 0, 0, 0);
        }
    }
    // epilogue: C/D layout col=lane&15, row=(lane>>4)*4+reg (m89-verified)
    const int prow0 = bm*128 + wm*64 + ((lane >> 4) << 2);
    const int pcol0 = bn*128 + wn*64 + frow;
    #pragma unroll
    for (int mi = 0; mi < 4; ++mi)
        #pragma unroll
        for (int ni = 0; ni < 4; ++ni)
            #pragma unroll
            for (int r = 0; r < 4; ++r)
                P[(size_t)(prow0 + mi*16 + r) * 1024 + pcol0 + ni*16] = acc[mi][ni][r];
}

// ---------------- Kernel B: per-row URNN pipeline (unchanged) -------------

template<int CONJ>
__device__ __forceinline__ void fft512(float2* buf, const float2* twid, int t){
    #pragma unroll
    for (int s = 1; s <= 9; ++s){
        int half = 1 << (s-1);
        int j  = t & (half-1);
        int i1 = ((t >> (s-1)) << s) + j;
        int i2 = i1 + half;
        float2 w = twid[j << (9-s)];
        if (CONJ) w.y = -w.y;
        float2 a  = buf[i1];
        float2 bb = cmul(w, buf[i2]);
        buf[i1] = make_float2(a.x+bb.x, a.y+bb.y);
        buf[i2] = make_float2(a.x-bb.x, a.y-bb.y);
        __syncthreads();
    }
}

__device__ __forceinline__ void reflect(float2* buf, const float* __restrict__ vre,
                                        const float* __restrict__ vim,
                                        float* red, int t){
    float2 z0 = buf[t], z1 = buf[t+256];
    float2 v0 = make_float2(vre[t],     vim[t]);
    float2 v1 = make_float2(vre[t+256], vim[t+256]);
    float pr = v0.x*z0.x + v0.y*z0.y + v1.x*z1.x + v1.y*z1.y;
    float pi = v0.x*z0.y - v0.y*z0.x + v1.x*z1.y - v1.y*z1.x;
    float nn = v0.x*v0.x + v0.y*v0.y + v1.x*v1.x + v1.y*v1.y;
    #pragma unroll
    for (int off = 32; off > 0; off >>= 1){
        pr += __shfl_down(pr, off);
        pi += __shfl_down(pi, off);
        nn += __shfl_down(nn, off);
    }
    int wave = t >> 6;
    if ((t & 63) == 0){ red[wave*3+0] = pr; red[wave*3+1] = pi; red[wave*3+2] = nn; }
    __syncthreads();
    pr = red[0] + red[3] + red[6] + red[9];
    pi = red[1] + red[4] + red[7] + red[10];
    nn = red[2] + red[5] + red[8] + red[11];
    float coef = 2.0f / nn;
    float2 c = make_float2(coef*pr, coef*pi);
    float2 d0 = cmul(c, v0), d1v = cmul(c, v1);
    buf[t]     = make_float2(z0.x - d0.x,  z0.y - d0.y);
    buf[t+256] = make_float2(z1.x - d1v.x, z1.y - d1v.y);
    __syncthreads();
}

__global__ __launch_bounds__(256) void urnn_kernel(
        const float* __restrict__ states,
        const float* __restrict__ b_h,
        const float* __restrict__ d1_w,
        const float* __restrict__ r1_re, const float* __restrict__ r1_im,
        const int* __restrict__ perm,
        const float* __restrict__ d2_w,
        const float* __restrict__ r2_re, const float* __restrict__ r2_im,
        const float* __restrict__ d3_w,
        float* __restrict__ out /* in: inputs_mul, out: result */)
{
    __shared__ float2 bufA[512];
    __shared__ float2 bufB[512];
    __shared__ float2 twid[256];
    __shared__ float  red[12];
    const int t = threadIdx.x;
    const int b = blockIdx.x;

    {
        float ang = -6.283185307179586f * (float)t / 512.0f;
        float sn, cs; __sincosf(ang, &sn, &cs);
        twid[t] = make_float2(cs, sn);
    }

    {
        float4 s4 = ((const float4*)(states + (size_t)b*1024))[t];
        float2 dw = ((const float2*)d1_w)[t];
        float sn, cs;
        __sincosf(dw.x, &sn, &cs);
        float2 z0 = cmul(make_float2(cs, sn), make_float2(s4.x, s4.y));
        __sincosf(dw.y, &sn, &cs);
        float2 z1 = cmul(make_float2(cs, sn), make_float2(s4.z, s4.w));
        bufA[__brev(2*t)   >> 23] = z0;
        bufA[__brev(2*t+1) >> 23] = z1;
    }
    __syncthreads();

    fft512<0>(bufA, twid, t);
    reflect(bufA, r1_re, r1_im, red, t);

    #pragma unroll
    for (int q = 0; q < 2; ++q){
        int i = t + q*256;
        int src = perm[i];
        float2 zv = bufA[src];
        float sn, cs; __sincosf(d2_w[i], &sn, &cs);
        zv = cmul(make_float2(cs, sn), zv);
        bufB[__brev(i) >> 23] = zv;
    }
    __syncthreads();

    fft512<1>(bufB, twid, t);
    reflect(bufB, r2_re, r2_im, red, t);

    float* orow = out + (size_t)b*1024;
    const float inv = 1.0f/512.0f;
    float2 res0, res1;
    {
        float2 c0 = ((const float2*)orow)[t];
        float2 z0 = bufB[t];
        float sn, cs; __sincosf(d3_w[t], &sn, &cs);
        float2 zz = cmul(make_float2(cs, sn), z0);
        float2 pre = make_float2(c0.x + zz.x*inv, c0.y + zz.y*inv);
        float norm = sqrtf(pre.x*pre.x + pre.y*pre.y);
        float sc = fmaxf(norm + b_h[t], 0.0f) / (norm + 1e-6f);
        res0 = make_float2(sc*pre.x, sc*pre.y);
    }
    {
        float2 c1 = ((const float2*)orow)[t+256];
        float2 z1 = bufB[t+256];
        float sn, cs; __sincosf(d3_w[t+256], &sn, &cs);
        float2 zz = cmul(make_float2(cs, sn), z1);
        float2 pre = make_float2(c1.x + zz.x*inv, c1.y + zz.y*inv);
        float norm = sqrtf(pre.x*pre.x + pre.y*pre.y);
        float sc = fmaxf(norm + b_h[t+256], 0.0f) / (norm + 1e-6f);
        res1 = make_float2(sc*pre.x, sc*pre.y);
    }
    __syncthreads();
    orow[t]       = res0.x;
    orow[t+512]   = res0.y;
    orow[t+256]   = res1.x;
    orow[t+768]   = res1.y;
}

extern "C" void kernel_launch(void* const* d_in, const int* in_sizes, int n_in,
                              void* d_out, int out_size, void* d_ws, size_t ws_size,
                              hipStream_t stream) {
    const float* inputs = (const float*)d_in[0];
    const float* states = (const float*)d_in[1];
    const float* w_ih   = (const float*)d_in[2];
    const float* b_h    = (const float*)d_in[3];
    const float* d1_w   = (const float*)d_in[4];
    const float* r1_re  = (const float*)d_in[5];
    const float* r1_im  = (const float*)d_in[6];
    const int*   perm   = (const int*)d_in[7];
    const float* d2_w   = (const float*)d_in[8];
    const float* r2_re  = (const float*)d_in[9];
    const float* r2_im  = (const float*)d_in[10];
    const float* d3_w   = (const float*)d_in[11];
    float* out = (float*)d_out;

    dim3 gA(8, 64);   // 1024/128 cols, 8192/128 rows
    gemm_bf16<<<gA, 256, 0, stream>>>(inputs, w_ih, out);
    urnn_kernel<<<BATCH, 256, 0, stream>>>(states, b_h, d1_w, r1_re, r1_im,
                                           perm, d2_w, r2_re, r2_im, d3_w, out);
}

// Round 6
// 159.833 us; speedup vs baseline: 1.5489x; 1.1709x over previous
//
#include <hip/hip_runtime.h>
#include <math.h>

#define BATCH 8192
#define NU 512      // NUM_UNITS
#define NIN 256     // NUM_IN

typedef __attribute__((ext_vector_type(8))) __bf16 bf16x8;
typedef __attribute__((ext_vector_type(4))) float f32x4;

__device__ __forceinline__ float2 cmul(float2 a, float2 b){
    return make_float2(a.x*b.x - a.y*b.y, a.x*b.y + a.y*b.x);
}
__device__ __forceinline__ float2 cadd(float2 a, float2 b){ return make_float2(a.x+b.x, a.y+b.y); }
__device__ __forceinline__ float2 csub(float2 a, float2 b){ return make_float2(a.x-b.x, a.y-b.y); }

// cis(sign * 2*pi*idx/512); idx in [0,256)
template<bool INV>
__device__ __forceinline__ float2 twid512(int idx){
    float ang = 0.012271846303085129f * (float)idx;   // 2*pi/512
    float sn, cs; __sincosf(INV ? ang : -ang, &sn, &cs);
    return make_float2(cs, sn);
}

// pack two f32 -> two bf16 (RNE) in one uint
__device__ __forceinline__ unsigned int pack2bf(float x, float y){
    unsigned int ux = __float_as_uint(x);
    ux = (ux + 0x7FFFu + ((ux >> 16) & 1u)) >> 16;
    unsigned int uy = __float_as_uint(y);
    uy = (uy + 0x7FFFu + ((uy >> 16) & 1u)) & 0xFFFF0000u;
    return ux | uy;
}

// ---------------- Kernel A: P = inputs @ w_ih^T via bf16 MFMA -------------
// 128x128 tile, BK=64, 256 threads (4 waves 2x2), XOR-swizzled LDS,
// LDS-staged coalesced epilogue.

__device__ __forceinline__ void stage_tile(const float* __restrict__ G,
                                           char* __restrict__ lds,
                                           int kb, int tid){
    const int r0 = tid >> 3;          // 0..31
    const int kc = (tid & 7) << 3;    // 0..56, 8 floats per thread
    #pragma unroll
    for (int it = 0; it < 4; ++it){
        const int row = r0 + (it << 5);
        const float* g = G + (size_t)row * NIN + kb + kc;
        float4 v0 = *(const float4*)g;
        float4 v1 = *(const float4*)(g + 4);
        int4 w;
        w.x = (int)pack2bf(v0.x, v0.y);
        w.y = (int)pack2bf(v0.z, v0.w);
        w.z = (int)pack2bf(v1.x, v1.y);
        w.w = (int)pack2bf(v1.z, v1.w);
        int off = (row << 7) + (kc << 1);   // row*128B + kc*2B
        off ^= (row & 7) << 4;              // XOR swizzle
        *(int4*)(lds + off) = w;
    }
}

__global__ __launch_bounds__(256) void gemm_bf16(const float* __restrict__ A,
                                                 const float* __restrict__ W,
                                                 float* __restrict__ P){
    __shared__ __align__(16) char smem[2 * 128*64*2];   // 32 KiB
    char* As = smem;
    char* Bs = smem + 128*64*2;
    const int tid  = threadIdx.x;
    const int lane = tid & 63, wv = tid >> 6;
    const int wm = wv >> 1, wn = wv & 1;     // 2x2 wave grid, 64x64 each
    const int bm = blockIdx.y, bn = blockIdx.x;

    const float* Ag = A + (size_t)bm * 128 * NIN;
    const float* Wg = W + (size_t)bn * 128 * NIN;

    f32x4 acc[4][4] = {};
    const int frow = lane & 15;
    const int kq   = (lane >> 4) << 4;       // byte offset of 8-bf16 k-group

    for (int kb = 0; kb < NIN; kb += 64){
        if (kb) __syncthreads();
        stage_tile(Ag, As, kb, tid);
        stage_tile(Wg, Bs, kb, tid);
        __syncthreads();
        #pragma unroll
        for (int ks = 0; ks < 2; ++ks){
            const int koff = kq + (ks << 6);
            bf16x8 a[4], b[4];
            #pragma unroll
            for (int i = 0; i < 4; ++i){
                const int ar = wm*64 + i*16 + frow;
                a[i] = *(const bf16x8*)(As + (((ar << 7) + koff) ^ ((ar & 7) << 4)));
                const int br = wn*64 + i*16 + frow;
                b[i] = *(const bf16x8*)(Bs + (((br << 7) + koff) ^ ((br & 7) << 4)));
            }
            #pragma unroll
            for (int mi = 0; mi < 4; ++mi)
                #pragma unroll
                for (int ni = 0; ni < 4; ++ni)
                    acc[mi][ni] = __builtin_amdgcn_mfma_f32_16x16x32_bf16(
                        a[mi], b[ni], acc[mi][ni], 0, 0, 0);
        }
    }

    // epilogue: stage 32-row quarters through LDS for coalesced float4 writes.
    // stg stride 132 floats (528B, 16B-aligned; 132%32=4 spreads banks).
    float* stg = (float*)smem;
    const int lr4 = (lane >> 4) << 2;
    #pragma unroll
    for (int q = 0; q < 4; ++q){
        __syncthreads();            // previous users of smem done
        if (wm == (q >> 1)){
            const int miBase = (q & 1) * 2;
            #pragma unroll
            for (int mj = 0; mj < 2; ++mj)
                #pragma unroll
                for (int ni = 0; ni < 4; ++ni)
                    #pragma unroll
                    for (int r = 0; r < 4; ++r)
                        stg[(lr4 + mj*16 + r)*132 + wn*64 + ni*16 + frow]
                            = acc[miBase + mj][ni][r];
        }
        __syncthreads();
        #pragma unroll
        for (int it = 0; it < 4; ++it){
            int idx = it*256 + tid;       // 0..1023: 32 rows x 32 float4
            int r32 = idx >> 5;
            int c4  = idx & 31;
            float4 v = *(const float4*)(stg + r32*132 + c4*4);
            int grow = bm*128 + (q >> 1)*64 + (q & 1)*32 + r32;
            *(float4*)(P + (size_t)grow*1024 + bn*128 + c4*4) = v;
        }
    }
}

// ---------------- Kernel B: wave-per-row URNN pipeline --------------------
// 1 wave = 1 batch row; 512-pt FFT as 64 lanes x 8 regs.
// Fwd: DIF natural->bitrev (3 register stages + 6 shfl_xor stages).
// Inv: DIT bitrev->natural (6 shfl_xor stages + 3 register stages, conj).

__device__ __forceinline__ void fft_fwd(float2 z[8], int l){
    // h=256 (m=1): pairs (r, r+4), j = r*64+l
    #pragma unroll
    for (int r = 0; r < 4; ++r){
        float2 w = twid512<false>(r*64 + l);
        float2 a = z[r], b = z[r+4];
        z[r]   = cadd(a, b);
        z[r+4] = cmul(w, csub(a, b));
    }
    // h=128 (m=2): pairs (g, g+2), g in {0,1,4,5}, j=(g&1)*64+l
    {
        float2 w0 = twid512<false>(2*l), w1 = twid512<false>(2*(64+l));
        const int gs[4] = {0,1,4,5};
        #pragma unroll
        for (int k = 0; k < 4; ++k){
            int g = gs[k];
            float2 w = (g & 1) ? w1 : w0;
            float2 a = z[g], b = z[g+2];
            z[g]   = cadd(a, b);
            z[g+2] = cmul(w, csub(a, b));
        }
    }
    // h=64 (m=4): pairs (g, g+1), g even, j=l
    {
        float2 w = twid512<false>(4*l);
        #pragma unroll
        for (int g = 0; g < 8; g += 2){
            float2 a = z[g], b = z[g+1];
            z[g]   = cadd(a, b);
            z[g+1] = cmul(w, csub(a, b));
        }
    }
    // shuffle stages h=32..1 (m=256/h): butterfly across lanes l ^ h
    #pragma unroll
    for (int h = 32; h >= 1; h >>= 1){
        int m = 256 / h;
        float2 w = twid512<false>(m * (l & (h-1)));
        bool low = (l & h) != 0;
        #pragma unroll
        for (int r = 0; r < 8; ++r){
            float2 p;
            p.x = __shfl_xor(z[r].x, h);
            p.y = __shfl_xor(z[r].y, h);
            z[r] = low ? cmul(w, csub(p, z[r])) : cadd(z[r], p);
        }
    }
}

__device__ __forceinline__ void fft_inv(float2 z[8], int l){
    // shuffle stages h=1..32 (m=256/h), conj twiddles
    #pragma unroll
    for (int h = 1; h <= 32; h <<= 1){
        int m = 256 / h;
        float2 w = twid512<true>(m * (l & (h-1)));
        bool low = (l & h) != 0;
        #pragma unroll
        for (int r = 0; r < 8; ++r){
            float2 p;
            p.x = __shfl_xor(z[r].x, h);
            p.y = __shfl_xor(z[r].y, h);
            float2 t = cmul(w, low ? z[r] : p);
            z[r] = low ? csub(p, t) : cadd(z[r], t);
        }
    }
    // h=64 (m=4): pairs (g, g+1), g even, j=l
    {
        float2 w = twid512<true>(4*l);
        #pragma unroll
        for (int g = 0; g < 8; g += 2){
            float2 b = cmul(w, z[g+1]);
            z[g+1] = csub(z[g], b);
            z[g]   = cadd(z[g], b);
        }
    }
    // h=128 (m=2): pairs (g, g+2), g in {0,1,4,5}, j=(g&1)*64+l
    {
        float2 w0 = twid512<true>(2*l), w1 = twid512<true>(2*(64+l));
        const int gs[4] = {0,1,4,5};
        #pragma unroll
        for (int k = 0; k < 4; ++k){
            int g = gs[k];
            float2 w = (g & 1) ? w1 : w0;
            float2 b = cmul(w, z[g+2]);
            z[g+2] = csub(z[g], b);
            z[g]   = cadd(z[g], b);
        }
    }
    // h=256 (m=1): pairs (r, r+4), j = r*64+l
    #pragma unroll
    for (int r = 0; r < 4; ++r){
        float2 w = twid512<true>(r*64 + l);
        float2 b = cmul(w, z[r+4]);
        z[r+4] = csub(z[r], b);
        z[r]   = cadd(z[r], b);
    }
}

__device__ __forceinline__ void wave_reflect(float2 z[8], const float2 v[8]){
    float pr = 0.f, pi = 0.f, nn = 0.f;
    #pragma unroll
    for (int r = 0; r < 8; ++r){
        pr += v[r].x*z[r].x + v[r].y*z[r].y;
        pi += v[r].x*z[r].y - v[r].y*z[r].x;
        nn += v[r].x*v[r].x + v[r].y*v[r].y;
    }
    #pragma unroll
    for (int off = 32; off > 0; off >>= 1){
        pr += __shfl_xor(pr, off);
        pi += __shfl_xor(pi, off);
        nn += __shfl_xor(nn, off);
    }
    float c2 = 2.0f / nn;
    float2 cc = make_float2(c2*pr, c2*pi);
    #pragma unroll
    for (int r = 0; r < 8; ++r)
        z[r] = csub(z[r], cmul(cc, v[r]));
}

__global__ __launch_bounds__(256) void urnn_wave(
        const float* __restrict__ states,
        const float* __restrict__ b_h,
        const float* __restrict__ d1_w,
        const float* __restrict__ r1_re, const float* __restrict__ r1_im,
        const int* __restrict__ perm,
        const float* __restrict__ d2_w,
        const float* __restrict__ r2_re, const float* __restrict__ r2_im,
        const float* __restrict__ d3_w,
        float* __restrict__ out /* in: inputs_mul, out: result */)
{
    __shared__ float2 zbuf[4][512];          // per-wave permutation buffer
    __shared__ float2 vb1[512];              // v1[rev(s)]
    __shared__ float2 t2[512];               // cis(d2[rev(s)])
    __shared__ unsigned short gidx[512];     // rev(perm[rev(s)])

    const int tid = threadIdx.x;
    const int l = tid & 63, wv = tid >> 6;

    // per-block tables (bit-reversed domain), shared by the 4 waves
    #pragma unroll
    for (int q = 0; q < 2; ++q){
        int s = tid + q*256;
        int i = __brev((unsigned)s) >> 23;          // rev9(s)
        vb1[s] = make_float2(r1_re[i], r1_im[i]);
        float sn, cs; __sincosf(d2_w[i], &sn, &cs);
        t2[s] = make_float2(cs, sn);
        gidx[s] = (unsigned short)(__brev((unsigned)perm[i]) >> 23);
    }
    __syncthreads();

    const int row = blockIdx.x * 4 + wv;
    const float* srow = states + (size_t)row * 1024;
    float* orow = out + (size_t)row * 1024;

    // preload inputs_mul (interleaved complex) — also removes the
    // read-after-overwrite hazard on orow
    float2 c[8];
    #pragma unroll
    for (int r = 0; r < 8; ++r) c[r] = ((const float2*)orow)[r*64 + l];

    // state load + diag1 (natural order: storage s = r*64+l holds element s)
    float2 z[8];
    #pragma unroll
    for (int r = 0; r < 8; ++r){
        int e = r*64 + l;
        float2 st = ((const float2*)srow)[e];
        float sn, cs; __sincosf(d1_w[e], &sn, &cs);
        z[r] = cmul(make_float2(cs, sn), st);
    }

    fft_fwd(z, l);                 // -> storage s holds X[rev(s)]

    { // reflection 1 in bit-reversed domain (elementwise => order-free)
        float2 v[8];
        #pragma unroll
        for (int r = 0; r < 8; ++r) v[r] = vb1[r*64 + l];
        wave_reflect(z, v);
    }

    // permutation + diag2, repacked to bitrev-for-DIT:
    // z'[s] = t2[s] * zstore[ gidx[s] ]
    {
        float2* zw = zbuf[wv];
        #pragma unroll
        for (int r = 0; r < 8; ++r) zw[r*64 + l] = z[r];
        __syncthreads();   // cheap safety; per-wave regions are disjoint
        #pragma unroll
        for (int r = 0; r < 8; ++r){
            int s = r*64 + l;
            z[r] = cmul(t2[s], zw[gidx[s]]);
        }
    }

    fft_inv(z, l);                 // -> natural order

    { // reflection 2 in natural domain (global v; L1-resident, coalesced)
        float2 v[8];
        #pragma unroll
        for (int r = 0; r < 8; ++r){
            int e = r*64 + l;
            v[r] = make_float2(r2_re[e], r2_im[e]);
        }
        wave_reflect(z, v);
    }

    // diag3 * (1/512) + inputs_mul + modReLU; write concat([re, im])
    const float inv = 1.0f/512.0f;
    #pragma unroll
    for (int r = 0; r < 8; ++r){
        int e = r*64 + l;
        float sn, cs; __sincosf(d3_w[e], &sn, &cs);
        float2 zz = cmul(make_float2(cs, sn), z[r]);
        float2 pre = make_float2(c[r].x + zz.x*inv, c[r].y + zz.y*inv);
        float nrm = sqrtf(pre.x*pre.x + pre.y*pre.y);
        float sc = fmaxf(nrm + b_h[e], 0.f) / (nrm + 1e-6f);
        orow[e]       = sc*pre.x;
        orow[e + 512] = sc*pre.y;
    }
}

extern "C" void kernel_launch(void* const* d_in, const int* in_sizes, int n_in,
                              void* d_out, int out_size, void* d_ws, size_t ws_size,
                              hipStream_t stream) {
    const float* inputs = (const float*)d_in[0];
    const float* states = (const float*)d_in[1];
    const float* w_ih   = (const float*)d_in[2];
    const float* b_h    = (const float*)d_in[3];
    const float* d1_w   = (const float*)d_in[4];
    const float* r1_re  = (const float*)d_in[5];
    const float* r1_im  = (const float*)d_in[6];
    const int*   perm   = (const int*)d_in[7];
    const float* d2_w   = (const float*)d_in[8];
    const float* r2_re  = (const float*)d_in[9];
    const float* r2_im  = (const float*)d_in[10];
    const float* d3_w   = (const float*)d_in[11];
    float* out = (float*)d_out;

    dim3 gA(8, 64);   // 1024/128 cols, 8192/128 rows
    gemm_bf16<<<gA, 256, 0, stream>>>(inputs, w_ih, out);
    urnn_wave<<<BATCH/4, 256, 0, stream>>>(states, b_h, d1_w, r1_re, r1_im,
                                           perm, d2_w, r2_re, r2_im, d3_w, out);
}